// Round 2
// baseline (818.827 us; speedup 1.0000x reference)
//
#include <hip/hip_runtime.h>
#include <hip/hip_bf16.h>

typedef unsigned short u16;
using bf16x8 = __attribute__((ext_vector_type(8))) short;
using f32x4  = __attribute__((ext_vector_type(4))) float;

__device__ __forceinline__ u16 f2b(float f) {          // fp32 -> bf16 RNE
    unsigned u = __float_as_uint(f);
    return (u16)((u + 0x7fffu + ((u >> 16) & 1u)) >> 16);
}
__device__ __forceinline__ float sigm(float x) { return 1.f / (1.f + expf(-x)); }

// pack 8 consecutive fp32 (16B-aligned) into a bf16x8 MFMA fragment slice
__device__ __forceinline__ bf16x8 pack8(const float* p) {
    float4 a = *(const float4*)p, b = *(const float4*)(p + 4);
    bf16x8 r;
    r[0] = (short)f2b(a.x); r[1] = (short)f2b(a.y);
    r[2] = (short)f2b(a.z); r[3] = (short)f2b(a.w);
    r[4] = (short)f2b(b.x); r[5] = (short)f2b(b.y);
    r[6] = (short)f2b(b.z); r[7] = (short)f2b(b.w);
    return r;
}

// 64-length fp32 dot: w is global (float4-aligned), s is LDS
__device__ __forceinline__ float dot64(const float* __restrict__ w, const float* s) {
    float acc = 0.f;
    #pragma unroll
    for (int i = 0; i < 16; ++i) {
        float4 v = ((const float4*)w)[i];
        acc += v.x * s[i*4] + v.y * s[i*4+1] + v.z * s[i*4+2] + v.w * s[i*4+3];
    }
    return acc;
}

// ---------------------------------------------------------------------------
// Kernel 1 (single block, 1024 threads): serial head, all fp32
//   sub = tanh(mask @ sub_W^T + sub_b)  -> out[seed,:], LDS
//   r0  = GRU(enc, sub)                 -> LDS
//   gi1 = r0 @ W_ih^T + b_ih            -> ws (fp32, 768)
// thread (d = tid>>2, g = tid&3): 64-length K-slice of output dim d.
// ---------------------------------------------------------------------------
__global__ __launch_bounds__(1024)
void k1_head(const float* __restrict__ enc, const float* __restrict__ mask,
             const float* __restrict__ W_ih, const float* __restrict__ W_hh,
             const float* __restrict__ b_ih, const float* __restrict__ b_hh,
             const float* __restrict__ sub_W, const float* __restrict__ sub_b,
             float* __restrict__ gi1, float* __restrict__ out,
             const int* __restrict__ seed_p)
{
    __shared__ float enc_s[256], mask_s[256], sub_s[256], r0_s[256];
    __shared__ float gi_s[768], gh_s[768];
    __shared__ float pA[1024], pB[1024];
    const int tid = threadIdx.x;
    if (tid < 256)       mask_s[tid]      = mask[tid];
    else if (tid < 512)  enc_s[tid - 256] = enc[tid - 256];
    __syncthreads();

    const int d = tid >> 2, g = tid & 3;

    // ---- sub = tanh(mask @ sub_W^T + sub_b) ----
    pA[tid] = dot64(sub_W + d * 256 + g * 64, mask_s + g * 64);
    __syncthreads();
    if (tid < 256) {
        float s = tanhf(pA[4*tid] + pA[4*tid+1] + pA[4*tid+2] + pA[4*tid+3] + sub_b[tid]);
        sub_s[tid] = s;
        out[(size_t)seed_p[0] * 256 + tid] = s;   // ent[seed] = sub
    }
    __syncthreads();

    // ---- gi0 = enc @ W_ih^T + b_ih ; gh0 = sub @ W_hh^T + b_hh ----
    for (int r = 0; r < 3; ++r) {
        const int j = r * 256 + d;
        pA[tid] = dot64(W_ih + (size_t)j * 256 + g * 64, enc_s + g * 64);
        pB[tid] = dot64(W_hh + (size_t)j * 256 + g * 64, sub_s + g * 64);
        __syncthreads();
        if (tid < 256) {
            const int jj = r * 256 + tid;
            gi_s[jj] = pA[4*tid] + pA[4*tid+1] + pA[4*tid+2] + pA[4*tid+3] + b_ih[jj];
            gh_s[jj] = pB[4*tid] + pB[4*tid+1] + pB[4*tid+2] + pB[4*tid+3] + b_hh[jj];
        }
        __syncthreads();
    }
    // ---- r0 = GRU combine ----
    if (tid < 256) {
        float rr = sigm(gi_s[tid] + gh_s[tid]);
        float zz = sigm(gi_s[256 + tid] + gh_s[256 + tid]);
        float nn = tanhf(gi_s[512 + tid] + rr * gh_s[512 + tid]);
        r0_s[tid] = (1.f - zz) * nn + zz * sub_s[tid];
    }
    __syncthreads();
    // ---- gi1 = r0 @ W_ih^T + b_ih  (shared by all edges) ----
    for (int r = 0; r < 3; ++r) {
        const int j = r * 256 + d;
        pA[tid] = dot64(W_ih + (size_t)j * 256 + g * 64, r0_s + g * 64);
        __syncthreads();
        if (tid < 256) {
            const int jj = r * 256 + tid;
            gi1[jj] = pA[4*tid] + pA[4*tid+1] + pA[4*tid+2] + pA[4*tid+3] + b_ih[jj];
        }
        __syncthreads();
    }
}

// ---------------------------------------------------------------------------
// Kernel 2a: gh[R,768] = rel_table[R,256] @ W_hh^T + b_hh  (MFMA 16x16x32)
// fp32 inputs converted to bf16 in-register (fp32 accumulate).
// A-frag: lane holds A[m=l&15][k=q*8+j]; B-frag: B[k=q*8+j][n=l&15]=W[n][k]
// -> both are 8 contiguous fp32 in row-major memory.
// ---------------------------------------------------------------------------
__global__ __launch_bounds__(64)
void k2_gh(const float* __restrict__ rel_table, const float* __restrict__ W_hh,
           const float* __restrict__ b_hh, float* __restrict__ gh, int R)
{
    const int l = threadIdx.x, m = l & 15, q = l >> 4;
    const int tt = blockIdx.y, jt = blockIdx.x;
    int trow = tt * 16 + m; if (trow >= R) trow = R - 1;     // clamp; store guarded
    const float* ab = rel_table + (size_t)trow * 256 + q * 8;
    const float* bb = W_hh + (size_t)(jt * 16 + m) * 256 + q * 8;
    f32x4 acc = {0.f, 0.f, 0.f, 0.f};
    #pragma unroll
    for (int kk = 0; kk < 8; ++kk) {
        bf16x8 a = pack8(ab + kk * 32);
        bf16x8 b = pack8(bb + kk * 32);
        acc = __builtin_amdgcn_mfma_f32_16x16x32_bf16(a, b, acc, 0, 0, 0);
    }
    const int col = jt * 16 + m;                 // C/D: col = lane&15
    const float bias = b_hh[col];
    #pragma unroll
    for (int i = 0; i < 4; ++i) {
        const int row = tt * 16 + q * 4 + i;     // C/D: row = (l>>4)*4 + reg
        if (row < R) gh[(size_t)row * 768 + col] = acc[i] + bias;
    }
}

// ---------------------------------------------------------------------------
// Kernel 2b: per-relation GRU combine -> rj (bf16, MFMA A-input) [R,256]
// ---------------------------------------------------------------------------
__global__ __launch_bounds__(256)
void k2_comb(const float* __restrict__ gh, const float* __restrict__ gi1,
             const float* __restrict__ rel_table, u16* __restrict__ rj)
{
    const int t = blockIdx.x, dd = threadIdx.x;
    const float gr = gh[(size_t)t * 768 + dd];
    const float gz = gh[(size_t)t * 768 + 256 + dd];
    const float gn = gh[(size_t)t * 768 + 512 + dd];
    const float r = sigm(gi1[dd] + gr);
    const float z = sigm(gi1[256 + dd] + gz);
    const float n = tanhf(gi1[512 + dd] + r * gn);
    const float h = rel_table[(size_t)t * 256 + dd];
    rj[(size_t)t * 256 + dd] = f2b((1.f - z) * n + z * h);
}

// ---------------------------------------------------------------------------
// Kernel 2c: obj[R,256] = tanh(rj @ obj_W^T + obj_b)  (MFMA, fp32 out)
// ---------------------------------------------------------------------------
__global__ __launch_bounds__(64)
void k2_obj(const u16* __restrict__ rj, const float* __restrict__ obj_W,
            const float* __restrict__ obj_b, float* __restrict__ obj, int R)
{
    const int l = threadIdx.x, m = l & 15, q = l >> 4;
    const int tt = blockIdx.y, jt = blockIdx.x;
    int trow = tt * 16 + m; if (trow >= R) trow = R - 1;
    const u16* ab = rj + (size_t)trow * 256 + q * 8;
    const float* bb = obj_W + (size_t)(jt * 16 + m) * 256 + q * 8;
    f32x4 acc = {0.f, 0.f, 0.f, 0.f};
    #pragma unroll
    for (int kk = 0; kk < 8; ++kk) {
        bf16x8 a = *(const bf16x8*)(ab + kk * 32);   // rj already bf16
        bf16x8 b = pack8(bb + kk * 32);
        acc = __builtin_amdgcn_mfma_f32_16x16x32_bf16(a, b, acc, 0, 0, 0);
    }
    const int col = jt * 16 + m;
    const float bias = obj_b[col];
    #pragma unroll
    for (int i = 0; i < 4; ++i) {
        const int row = tt * 16 + q * 4 + i;
        if (row < R) obj[(size_t)row * 256 + col] = tanhf(acc[i] + bias);
    }
}

// ---------------------------------------------------------------------------
// Kernel 3: per-edge scatter (pure bandwidth). 64 lanes per 1KB row, 16B/lane.
//   out[tail_ids[e]] = state[e]==1 ? entity[origin[e]] : obj[rel_ids[e]]
// ---------------------------------------------------------------------------
__global__ __launch_bounds__(256)
void k3_scatter(const float* __restrict__ entity, const float* __restrict__ obj,
                const int* __restrict__ rel_ids, const int* __restrict__ tail_ids,
                const int* __restrict__ state, const int* __restrict__ origin,
                float* __restrict__ out, int E)
{
    const long long gidx = (long long)blockIdx.x * 256 + threadIdx.x;
    const int e = (int)(gidx >> 6);
    if (e >= E) return;
    const int c = ((int)gidx & 63) * 4;
    const float* src = (state[e] == 1) ? entity + (size_t)origin[e] * 256
                                       : obj + (size_t)rel_ids[e] * 256;
    *(float4*)(out + (size_t)tail_ids[e] * 256 + c) = *(const float4*)(src + c);
}

extern "C" void kernel_launch(void* const* d_in, const int* in_sizes, int n_in,
                              void* d_out, int out_size, void* d_ws, size_t ws_size,
                              hipStream_t stream)
{
    const float* enc       = (const float*)d_in[0];
    const float* mask      = (const float*)d_in[1];
    const float* entity    = (const float*)d_in[2];
    const float* rel_table = (const float*)d_in[3];
    const float* W_ih      = (const float*)d_in[4];
    const float* W_hh      = (const float*)d_in[5];
    const float* b_ih      = (const float*)d_in[6];
    const float* b_hh      = (const float*)d_in[7];
    const float* sub_W     = (const float*)d_in[8];
    const float* sub_b     = (const float*)d_in[9];
    const float* obj_W     = (const float*)d_in[10];
    const float* obj_b     = (const float*)d_in[11];
    const int* rel_ids     = (const int*)d_in[12];
    const int* tail_ids    = (const int*)d_in[13];
    const int* state       = (const int*)d_in[14];
    const int* origin      = (const int*)d_in[15];
    const int* seed_p      = (const int*)d_in[16];
    float* out = (float*)d_out;

    const int E = in_sizes[12];
    const int R = in_sizes[3] / 256;

    // ws layout (~4.6 MB): gi1 | gh fp32 | rj bf16 | obj fp32
    float* gi1 = (float*)d_ws;                     // 1024 fp32 (768 used)
    float* gh  = gi1 + 1024;                       // R*768 fp32
    u16*   rj  = (u16*)(gh + (size_t)R * 768);     // R*256 bf16
    float* obj = (float*)(rj + (size_t)R * 256);   // R*256 fp32

    k1_head<<<1, 1024, 0, stream>>>(enc, mask, W_ih, W_hh, b_ih, b_hh,
                                    sub_W, sub_b, gi1, out, seed_p);
    dim3 g_gh(48, (R + 15) / 16);
    k2_gh<<<g_gh, 64, 0, stream>>>(rel_table, W_hh, b_hh, gh, R);
    k2_comb<<<R, 256, 0, stream>>>(gh, gi1, rel_table, rj);
    dim3 g_obj(16, (R + 15) / 16);
    k2_obj<<<g_obj, 64, 0, stream>>>(rj, obj_W, obj_b, obj, R);
    const int blocks = (int)(((long long)E * 64 + 255) / 256);
    k3_scatter<<<blocks, 256, 0, stream>>>(entity, obj, rel_ids, tail_ids,
                                           state, origin, out, E);
}